// Round 11
// baseline (290.475 us; speedup 1.0000x reference)
//
#include <hip/hip_runtime.h>
#include <hip/hip_bf16.h>
#include <math.h>
#include <stdint.h>

#define NTOK 21824

typedef __attribute__((ext_vector_type(8)))  short bf16x8;
typedef __attribute__((ext_vector_type(4)))  float f32x4;
typedef __attribute__((ext_vector_type(16))) float f32x16;

__device__ __forceinline__ uint32_t f2bf(float f) {
    uint32_t u = __builtin_bit_cast(uint32_t, f);
    return (u + 0x7FFFu + ((u >> 16) & 1u)) >> 16;   // RNE
}
__device__ __forceinline__ uint32_t pkbf2(float lo, float hi) {
    __hip_bfloat162 h = __float22bfloat162_rn(float2{lo, hi});
    uint32_t r; __builtin_memcpy(&r, &h, 4);         // v_cvt_pk_bf16_f32
    return r;
}

// ws layout (uint16): cls_Wh @0, box_Wh @65536, cls_Wo @131072, box_Wo(pad 16x256) @151552,
// hidden buffer @155648 (nb batches x NTOK x 512 bf16)
#define WOFF_CWH 0
#define WOFF_BWH 65536
#define WOFF_CWO 131072
#define WOFF_BWO 151552
#define HID_OFF  155648

__global__ void prep_weights(const float* __restrict__ cWh, const float* __restrict__ cWo,
                             const float* __restrict__ bWh, const float* __restrict__ bWo,
                             uint16_t* __restrict__ ws) {
    int i = blockIdx.x * 256 + threadIdx.x;
    if (i >= 155648) return;
    uint32_t v;
    if (i < 65536)       v = f2bf(cWh[i]);
    else if (i < 131072) v = f2bf(bWh[i - 65536]);
    else if (i < 151552) v = f2bf(cWo[i - 131072]);
    else { int j = i - 151552; v = (j < 1024) ? f2bf(bWo[j]) : 0u; }
    ws[i] = (uint16_t)v;
}

__device__ __forceinline__ void level_lookup(
    int n0, const float* fm0, const float* fm1, const float* fm2,
    const float* fm3, const float* fm4, const float*& fm, int& off, int& ls) {
    if      (n0 < 16384) { fm = fm0; off = 0;     ls = 7; }
    else if (n0 < 20480) { fm = fm1; off = 16384; ls = 6; }
    else if (n0 < 21504) { fm = fm2; off = 20480; ls = 5; }
    else if (n0 < 21760) { fm = fm3; off = 21504; ls = 4; }
    else                 { fm = fm4; off = 21760; ls = 3; }
}

// ======================= k1: X -> hidden (G1, both heads) =======================
__global__ __launch_bounds__(512, 4) void dfd_g1(
    const float* __restrict__ fm0, const float* __restrict__ fm1,
    const float* __restrict__ fm2, const float* __restrict__ fm3,
    const float* __restrict__ fm4,
    const float* __restrict__ cls_bh, const float* __restrict__ box_bh,
    const uint16_t* __restrict__ wbf,
    uint16_t* __restrict__ hid,     // [nb][NTOK][512] bf16 (chunk-local batches)
    int b0)
{
    __shared__ uint16_t Xs[64 * 256];   // [t][f^sw], sw = (t&7)<<3

    const int tid  = threadIdx.x;
    const int lane = tid & 63;
    const int w    = tid >> 6;          // wave 0..7
    const int col  = lane & 31;
    const int hi   = lane >> 5;
    const int n0   = blockIdx.x * 64;
    const int lb   = blockIdx.y;        // chunk-local batch
    const int b    = b0 + lb;           // global batch

    const float* fm; int off, ls;
    level_lookup(n0, fm0, fm1, fm2, fm3, fm4, fm, off, ls);
    const int hw = 1 << (2 * ls);
    const int p0 = n0 - off;

    // ---- stage: fm[b][f][p0+t] -> Xs[t][f^sw], packed b128 writes
    {
        const int t  = lane;
        const int sw = (t & 7) << 3;
        const float* src = fm + (size_t)b * 256 * hw + p0 + t;
        #pragma unroll
        for (int i = 0; i < 4; ++i) {
            const int f0 = w * 8 + i * 64;
            float x[8];
            #pragma unroll
            for (int e = 0; e < 8; ++e) x[e] = src[(size_t)(f0 + e) * hw];
            uint4 pk;
            pk.x = pkbf2(x[0], x[1]); pk.y = pkbf2(x[2], x[3]);
            pk.z = pkbf2(x[4], x[5]); pk.w = pkbf2(x[6], x[7]);
            *reinterpret_cast<uint4*>(&Xs[t * 256 + (f0 ^ sw)]) = pk;
        }
    }
    __syncthreads();    // the only barrier in k1

    // ---- G1 (32x32x16): C[h][t]. Wave w owns hh in [w*64, w*64+64)
    //      (hh<256 = cls hidden, hh>=256 = box hidden). Verified math.
    f32x16 acc[2][2];   // [mt = hh 32-tile][nt = token 32-tile]
    #pragma unroll
    for (int mt = 0; mt < 2; ++mt)
        #pragma unroll
        for (int nt = 0; nt < 2; ++nt)
            #pragma unroll
            for (int e = 0; e < 16; ++e) acc[mt][nt][e] = 0.f;

    const int hh0 = w * 64;
    const uint16_t* Wbase = (w < 4) ? wbf + WOFF_CWH + hh0 * 256
                                    : wbf + WOFF_BWH + (hh0 - 256) * 256;
    const int kh = hi * 8;
    const uint16_t* Wr = Wbase + col * 256 + kh;
    const int sw0 = (col & 7) << 3;

    #pragma unroll
    for (int ks = 0; ks < 16; ++ks) {
        const bf16x8 a0 = *(const bf16x8*)(Wr + ks * 16);
        const bf16x8 a1 = *(const bf16x8*)(Wr + 8192 + ks * 16);
        const int kx = (ks * 16 + kh) ^ sw0;
        const bf16x8 x0 = *(const bf16x8*)&Xs[col * 256 + kx];
        const bf16x8 x1 = *(const bf16x8*)&Xs[(32 + col) * 256 + kx];
        acc[0][0] = __builtin_amdgcn_mfma_f32_32x32x16_bf16(a0, x0, acc[0][0], 0, 0, 0);
        acc[0][1] = __builtin_amdgcn_mfma_f32_32x32x16_bf16(a0, x1, acc[0][1], 0, 0, 0);
        acc[1][0] = __builtin_amdgcn_mfma_f32_32x32x16_bf16(a1, x0, acc[1][0], 0, 0, 0);
        acc[1][1] = __builtin_amdgcn_mfma_f32_32x32x16_bf16(a1, x1, acc[1][1], 0, 0, 0);
    }

    // ---- epilogue: bias+ReLU, write hidden to global.
    //      Wave w covers hh0..hh0+63 = exactly one 128B line per token.
    const float* bh_ = (w < 4) ? cls_bh + hh0 : box_bh + (hh0 - 256);
    #pragma unroll
    for (int nt = 0; nt < 2; ++nt) {
        const int t = nt * 32 + col;
        uint16_t* hrow = hid + ((size_t)lb * NTOK + n0 + t) * 512 + hh0;
        #pragma unroll
        for (int mt = 0; mt < 2; ++mt) {
            #pragma unroll
            for (int g = 0; g < 4; ++g) {
                const int hb = mt * 32 + 8 * g + 4 * hi;   // hidden idx = hh0+hb+(0..3)
                const f32x4 bv = *(const f32x4*)(bh_ + hb);
                const float v0 = fmaxf(acc[mt][nt][4 * g + 0] + bv[0], 0.f);
                const float v1 = fmaxf(acc[mt][nt][4 * g + 1] + bv[1], 0.f);
                const float v2 = fmaxf(acc[mt][nt][4 * g + 2] + bv[2], 0.f);
                const float v3 = fmaxf(acc[mt][nt][4 * g + 3] + bv[3], 0.f);
                uint2 pk; pk.x = pkbf2(v0, v1); pk.y = pkbf2(v2, v3);
                *reinterpret_cast<uint2*>(hrow + hb) = pk;
            }
        }
    }
}

// ======================= k2: hidden -> output (G2 + decode) =======================
__global__ __launch_bounds__(256, 6) void dfd_g2(
    const float* __restrict__ cls_bo, const float* __restrict__ box_bo,
    const uint16_t* __restrict__ wbf,
    const uint16_t* __restrict__ hid,
    float* __restrict__ out,
    int b0)
{
    const int tid  = threadIdx.x;
    const int lane = tid & 63;
    const int w    = tid >> 6;          // wave 0..3, each owns 16 tokens
    const int r    = lane & 15;
    const int q    = lane >> 4;
    const int n0   = blockIdx.x * 64;
    const int lb   = blockIdx.y;
    const int b    = b0 + lb;
    const int t0   = n0 + w * 16;       // first token of this wave

    int off, ls; const float* fm_unused;
    level_lookup(n0, nullptr, nullptr, nullptr, nullptr, nullptr, fm_unused, off, ls);
    const int dim = 1 << ls;
    const int p0  = n0 - off;

    // C[out][tok]: A = Wo rows (out), B = hidden (k-contiguous per token, from L3)
    f32x4 c[6];
    #pragma unroll
    for (int m = 0; m < 6; ++m) c[m] = {0.f, 0.f, 0.f, 0.f};

    const uint16_t* hrow = hid + ((size_t)lb * NTOK + t0 + r) * 512 + q * 8;
    const uint16_t* WoA  = wbf + WOFF_CWO + r * 256 + q * 8;
    const uint16_t* WoB  = wbf + WOFF_BWO + r * 256 + q * 8;

    #pragma unroll
    for (int kq = 0; kq < 8; ++kq) {
        const bf16x8 hbc = *(const bf16x8*)(hrow + kq * 32);          // cls hidden
        const bf16x8 hbb = *(const bf16x8*)(hrow + 256 + kq * 32);    // box hidden
        #pragma unroll
        for (int m = 0; m < 5; ++m) {
            const bf16x8 a = *(const bf16x8*)(WoA + m * 4096 + kq * 32);
            c[m] = __builtin_amdgcn_mfma_f32_16x16x32_bf16(a, hbc, c[m], 0, 0, 0);
        }
        const bf16x8 ab = *(const bf16x8*)(WoB + kq * 32);
        c[5] = __builtin_amdgcn_mfma_f32_16x16x32_bf16(ab, hbb, c[5], 0, 0, 0);
    }

    // ---- stores: one wave writes all 84 outs of its 16 tokens in one burst.
    //      D mapping: col = r (token), row = q*4+jj (out within tile).
    float* orow = out + ((size_t)b * NTOK + t0 + r) * 84;
    #pragma unroll
    for (int m = 0; m < 5; ++m) {
        const f32x4 bo = *(const f32x4*)(cls_bo + m * 16 + q * 4);
        f32x4 v;
        #pragma unroll
        for (int jj = 0; jj < 4; ++jj) v[jj] = c[m][jj] + bo[jj];
        *(f32x4*)(orow + m * 16 + q * 4) = v;
    }
    if (q == 0) {   // box rows 0..3 (padded Wo rows 4..15 are zero)
        const f32x4 bo = *(const f32x4*)box_bo;
        const float inv = 1.0f / (float)dim;
        const int p = p0 + w * 16 + r;
        const float d0 = tanhf(c[5][0] + bo[0]);
        const float d1 = tanhf(c[5][1] + bo[1]);
        const float d2 = tanhf(c[5][2] + bo[2]);
        const float d3 = tanhf(c[5][3] + bo[3]);
        f32x4 v;
        v[0] = ((float)(p & (dim - 1)) + 0.5f) * inv + 0.1f * d0;
        v[1] = ((float)(p >> ls) + 0.5f) * inv + 0.1f * d1;
        v[2] = exp2f(d2) * inv;
        v[3] = exp2f(d3) * inv;
        *(f32x4*)(orow + 80) = v;
    }
}

// ======================= fallback: round-10 fused kernel =======================
__global__ __launch_bounds__(512, 4) void dfd_fused(
    const float* __restrict__ fm0, const float* __restrict__ fm1,
    const float* __restrict__ fm2, const float* __restrict__ fm3,
    const float* __restrict__ fm4,
    const float* __restrict__ cls_bh, const float* __restrict__ cls_bo,
    const float* __restrict__ box_bh, const float* __restrict__ box_bo,
    const uint16_t* __restrict__ wbf,
    float* __restrict__ out)
{
    __shared__ uint16_t LB[64 * 512];
    uint16_t* Xs = LB;
    uint16_t* Hs = LB;

    const int tid  = threadIdx.x;
    const int lane = tid & 63;
    const int w    = tid >> 6;
    const int r    = lane & 15;
    const int q    = lane >> 4;
    const int col  = lane & 31;
    const int hi   = lane >> 5;
    const int n0   = blockIdx.x * 64;
    const int b    = blockIdx.y;

    const float* fm; int off, ls;
    level_lookup(n0, fm0, fm1, fm2, fm3, fm4, fm, off, ls);
    const int dim = 1 << ls;
    const int hw  = 1 << (2 * ls);
    const int p0  = n0 - off;

    {
        const int t  = lane;
        const int sw = (t & 7) << 3;
        const float* src = fm + (size_t)b * 256 * hw + p0 + t;
        #pragma unroll
        for (int i = 0; i < 4; ++i) {
            const int f0 = w * 8 + i * 64;
            float x[8];
            #pragma unroll
            for (int e = 0; e < 8; ++e) x[e] = src[(size_t)(f0 + e) * hw];
            uint4 pk;
            pk.x = pkbf2(x[0], x[1]); pk.y = pkbf2(x[2], x[3]);
            pk.z = pkbf2(x[4], x[5]); pk.w = pkbf2(x[6], x[7]);
            *reinterpret_cast<uint4*>(&Xs[t * 256 + (f0 ^ sw)]) = pk;
        }
    }
    __syncthreads();

    f32x16 acc[2][2];
    {
        #pragma unroll
        for (int mt = 0; mt < 2; ++mt)
            #pragma unroll
            for (int nt = 0; nt < 2; ++nt)
                #pragma unroll
                for (int e = 0; e < 16; ++e) acc[mt][nt][e] = 0.f;

        const int hh0 = w * 64;
        const uint16_t* Wbase = (w < 4) ? wbf + WOFF_CWH + hh0 * 256
                                        : wbf + WOFF_BWH + (hh0 - 256) * 256;
        const int kh = hi * 8;
        const uint16_t* Wr = Wbase + col * 256 + kh;
        const int sw0 = (col & 7) << 3;

        #pragma unroll
        for (int ks = 0; ks < 16; ++ks) {
            const bf16x8 a0 = *(const bf16x8*)(Wr + ks * 16);
            const bf16x8 a1 = *(const bf16x8*)(Wr + 8192 + ks * 16);
            const int kx = (ks * 16 + kh) ^ sw0;
            const bf16x8 x0 = *(const bf16x8*)&Xs[col * 256 + kx];
            const bf16x8 x1 = *(const bf16x8*)&Xs[(32 + col) * 256 + kx];
            acc[0][0] = __builtin_amdgcn_mfma_f32_32x32x16_bf16(a0, x0, acc[0][0], 0, 0, 0);
            acc[0][1] = __builtin_amdgcn_mfma_f32_32x32x16_bf16(a0, x1, acc[0][1], 0, 0, 0);
            acc[1][0] = __builtin_amdgcn_mfma_f32_32x32x16_bf16(a1, x0, acc[1][0], 0, 0, 0);
            acc[1][1] = __builtin_amdgcn_mfma_f32_32x32x16_bf16(a1, x1, acc[1][1], 0, 0, 0);
        }
    }
    __syncthreads();

    {
        const int hh0 = w * 64;
        const float* bh_ = (w < 4) ? cls_bh + hh0 : box_bh + (hh0 - 256);
        #pragma unroll
        for (int mt = 0; mt < 2; ++mt) {
            #pragma unroll
            for (int nt = 0; nt < 2; ++nt) {
                const int t   = nt * 32 + col;
                const int swt = (t & 7) << 3;
                #pragma unroll
                for (int g = 0; g < 4; ++g) {
                    const int hb = mt * 32 + 8 * g + 4 * hi;
                    const f32x4 bv = *(const f32x4*)(bh_ + hb);
                    const float v0 = fmaxf(acc[mt][nt][4 * g + 0] + bv[0], 0.f);
                    const float v1 = fmaxf(acc[mt][nt][4 * g + 1] + bv[1], 0.f);
                    const float v2 = fmaxf(acc[mt][nt][4 * g + 2] + bv[2], 0.f);
                    const float v3 = fmaxf(acc[mt][nt][4 * g + 3] + bv[3], 0.f);
                    uint2 pk; pk.x = pkbf2(v0, v1); pk.y = pkbf2(v2, v3);
                    *reinterpret_cast<uint2*>(&Hs[t * 512 + ((hh0 + hb) ^ swt)]) = pk;
                }
            }
        }
    }
    __syncthreads();

    if (w < 5) {
        f32x4 c[4];
        #pragma unroll
        for (int m = 0; m < 4; ++m) c[m] = {0.f, 0.f, 0.f, 0.f};
        const uint16_t* Bw = wbf + WOFF_CWO + (w * 16 + r) * 256 + q * 8;
        #pragma unroll
        for (int kq = 0; kq < 8; ++kq) {
            const bf16x8 bfr = *(const bf16x8*)(Bw + kq * 32);
            #pragma unroll
            for (int m = 0; m < 4; ++m) {
                const int t = m * 16 + r;
                const int kcol = (kq * 32 + q * 8) ^ ((t & 7) << 3);
                const bf16x8 a = *(const bf16x8*)&Hs[t * 512 + kcol];
                c[m] = __builtin_amdgcn_mfma_f32_16x16x32_bf16(a, bfr, c[m], 0, 0, 0);
            }
        }
        const float bo_l = cls_bo[w * 16 + r];
        #pragma unroll
        for (int m = 0; m < 4; ++m)
            #pragma unroll
            for (int jj = 0; jj < 4; ++jj)
                out[((size_t)b * NTOK + n0 + m * 16 + q * 4 + jj) * 84 + w * 16 + r]
                    = c[m][jj] + bo_l;
    } else if (w < 7) {
        const int m0 = (w - 5) * 2;
        f32x4 c[2];
        c[0] = {0.f, 0.f, 0.f, 0.f}; c[1] = {0.f, 0.f, 0.f, 0.f};
        const uint16_t* Bw = wbf + WOFF_BWO + r * 256 + q * 8;
        #pragma unroll
        for (int kq = 0; kq < 8; ++kq) {
            const bf16x8 bfr = *(const bf16x8*)(Bw + kq * 32);
            #pragma unroll
            for (int mm = 0; mm < 2; ++mm) {
                const int t = (m0 + mm) * 16 + r;
                const int kcol = 256 + ((kq * 32 + q * 8) ^ ((t & 7) << 3));
                const bf16x8 a = *(const bf16x8*)&Hs[t * 512 + kcol];
                c[mm] = __builtin_amdgcn_mfma_f32_16x16x32_bf16(a, bfr, c[mm], 0, 0, 0);
            }
        }
        if (r < 4) {
            const float bo_l = box_bo[r];
            const float inv  = 1.0f / (float)dim;
            #pragma unroll
            for (int mm = 0; mm < 2; ++mm)
                #pragma unroll
                for (int jj = 0; jj < 4; ++jj) {
                    const int t = (m0 + mm) * 16 + q * 4 + jj;
                    const int p = p0 + t;
                    const float d = tanhf(c[mm][jj] + bo_l);
                    float val;
                    if (r == 0)      val = ((float)(p & (dim - 1)) + 0.5f) * inv + 0.1f * d;
                    else if (r == 1) val = ((float)(p >> ls) + 0.5f) * inv + 0.1f * d;
                    else             val = exp2f(d) * inv;
                    out[((size_t)b * NTOK + n0 + t) * 84 + 80 + r] = val;
                }
        }
    }
}

extern "C" void kernel_launch(void* const* d_in, const int* in_sizes, int n_in,
                              void* d_out, int out_size, void* d_ws, size_t ws_size,
                              hipStream_t stream) {
    uint16_t* ws = (uint16_t*)d_ws;
    prep_weights<<<608, 256, 0, stream>>>(
        (const float*)d_in[5],  (const float*)d_in[7],
        (const float*)d_in[9],  (const float*)d_in[11], ws);

    const size_t HID_B_PER_BATCH = (size_t)NTOK * 512 * 2;   // 22,347,776 B
    const size_t W_BYTES = (size_t)HID_OFF * 2;
    int nb = 0;
    if      (ws_size >= W_BYTES + 4 * HID_B_PER_BATCH) nb = 4;   // L3-resident sweet spot
    else if (ws_size >= W_BYTES + 2 * HID_B_PER_BATCH) nb = 2;
    else if (ws_size >= W_BYTES + 1 * HID_B_PER_BATCH) nb = 1;

    if (nb > 0) {
        uint16_t* hid = ws + HID_OFF;
        for (int b0 = 0; b0 < 8; b0 += nb) {
            dim3 g(NTOK / 64, nb);
            dfd_g1<<<g, 512, 0, stream>>>(
                (const float*)d_in[0], (const float*)d_in[1], (const float*)d_in[2],
                (const float*)d_in[3], (const float*)d_in[4],
                (const float*)d_in[6], (const float*)d_in[10],
                ws, hid, b0);
            dfd_g2<<<g, 256, 0, stream>>>(
                (const float*)d_in[8], (const float*)d_in[12],
                ws, hid, (float*)d_out, b0);
        }
    } else {
        dim3 grid(NTOK / 64, 8);
        dfd_fused<<<grid, 512, 0, stream>>>(
            (const float*)d_in[0], (const float*)d_in[1], (const float*)d_in[2],
            (const float*)d_in[3], (const float*)d_in[4],
            (const float*)d_in[6],  (const float*)d_in[8],
            (const float*)d_in[10], (const float*)d_in[12],
            ws, (float*)d_out);
    }
}